// Round 3
// baseline (1147.196 us; speedup 1.0000x reference)
//
#include <hip/hip_runtime.h>
#include <stdint.h>

#define B 8192
#define T 512
#define K 24

// Exact first-index argmax over 24 values via tournament tree (depth 5).
// Every merge pairs a lower-index range against a higher one and keeps the
// lower on ties (strict > for the higher) => identical to jnp.argmax.
__device__ __forceinline__ void argmax24(const float s[K], float& mOut, int& pOut) {
    float v[12]; int idx[12];
#pragma unroll
    for (int p = 0; p < 12; ++p) {
        bool gt = s[2*p+1] > s[2*p];
        v[p]   = gt ? s[2*p+1] : s[2*p];
        idx[p] = gt ? 2*p+1 : 2*p;
    }
#pragma unroll
    for (int p = 0; p < 6; ++p) {
        bool gt = v[2*p+1] > v[2*p];
        v[p]   = gt ? v[2*p+1] : v[2*p];
        idx[p] = gt ? idx[2*p+1] : idx[2*p];
    }
#pragma unroll
    for (int p = 0; p < 3; ++p) {
        bool gt = v[2*p+1] > v[2*p];
        v[p]   = gt ? v[2*p+1] : v[2*p];
        idx[p] = gt ? idx[2*p+1] : idx[2*p];
    }
    bool g01 = v[1] > v[0];
    float vx = g01 ? v[1] : v[0];
    int   ix = g01 ? idx[1] : idx[0];
    bool g2  = v[2] > vx;
    mOut = g2 ? v[2] : vx;
    pOut = g2 ? idx[2] : ix;
}

// ---------------------------------------------------------------------------
// Forward Viterbi, barrier-free. 8 lanes per batch (3 tag columns each), so a
// 64-lane wave holds 8 independent batches; alpha exchange happens through LDS
// but only within one wave => program order + lgkmcnt give correctness with NO
// __syncthreads. 256 threads/block, 256 blocks, 1 wave/SIMD.
// WS=true: bp -> bp_ws[b][t][c] bytes, last_tag -> tag_ws[b][T-1].
// WS=false: bp -> out[b][t] bytes 72..95, last_tag -> out[b][0] word 18.
// ---------------------------------------------------------------------------
template<bool WS>
__global__ __launch_bounds__(256, 2) void crf_forward(
    const float* __restrict__ inp,    // [B, T, K]
    const float* __restrict__ trans,  // [K, K] (prev i -> cur j)
    float* __restrict__ out,
    uint8_t* __restrict__ bp_ws,
    uint8_t* __restrict__ tag_ws)
{
    __shared__ float alpha[2][4][8][K];   // [buf][wave][group][tag]

    const int tid  = threadIdx.x;
    const int w    = tid >> 6;
    const int lane = tid & 63;
    const int g    = lane >> 3;           // batch group within wave
    const int l    = lane & 7;            // lane within group
    const int c0   = 3 * l;               // first of this lane's 3 columns
    const int b    = blockIdx.x * 32 + w * 8 + g;

    // three transition columns in registers (72 VGPRs)
    float tc0[K], tc1[K], tc2[K];
#pragma unroll
    for (int i = 0; i < K; ++i) {
        tc0[i] = trans[i*K + c0];
        tc1[i] = trans[i*K + c0 + 1];
        tc2[i] = trans[i*K + c0 + 2];
    }

    const float* eb  = inp + (size_t)b * T * K;
    uint32_t*    obw = (uint32_t*)out + (size_t)b * T * K;
    uint8_t*     bpb = WS ? (bp_ws + (size_t)b * T * K) : nullptr;

    float* al0 = &alpha[0][w][g][0];
    float* al1 = &alpha[1][w][g][0];

    // t = 0
    al0[c0]     = eb[c0];
    al0[c0 + 1] = eb[c0 + 1];
    al0[c0 + 2] = eb[c0 + 2];

    // emissions for t = 1 (prefetched)
    float e0 = eb[K + c0], e1 = eb[K + c0 + 1], e2 = eb[K + c0 + 2];

    int cur = 0;
#pragma unroll 1
    for (int t = 1; t < T; ++t) {
        // prefetch next step's emissions
        const float* ep = eb + (size_t)(t + 1 < T ? t + 1 : t) * K + c0;
        float f0 = ep[0], f1 = ep[1], f2 = ep[2];

        const float* ac = cur ? al1 : al0;
        float*       an = cur ? al0 : al1;

        float a[K];
#pragma unroll
        for (int c = 0; c < 6; ++c) {
            float4 v = *(const float4*)(ac + 4*c);
            a[4*c] = v.x; a[4*c+1] = v.y; a[4*c+2] = v.z; a[4*c+3] = v.w;
        }

        float s0[K], s1[K], s2[K];
#pragma unroll
        for (int i = 0; i < K; ++i) {
            s0[i] = a[i] + tc0[i];
            s1[i] = a[i] + tc1[i];
            s2[i] = a[i] + tc2[i];
        }
        float m0, m1, m2; int p0, p1, p2;
        argmax24(s0, m0, p0);
        argmax24(s1, m1, p1);
        argmax24(s2, m2, p2);

        an[c0]     = m0 + e0;
        an[c0 + 1] = m1 + e1;
        an[c0 + 2] = m2 + e2;

        if (WS) {
            uint8_t* d = bpb + (size_t)t * K + c0;
            d[0] = (uint8_t)p0; d[1] = (uint8_t)p1; d[2] = (uint8_t)p2;
        } else {
            uint8_t* d = (uint8_t*)(obw + (size_t)t * K + 18) + c0;
            d[0] = (uint8_t)p0; d[1] = (uint8_t)p1; d[2] = (uint8_t)p2;
        }

        e0 = f0; e1 = f1; e2 = f2;
        cur ^= 1;
    }

    // last_tag = first-index argmax of alpha_{T-1}; group-lane 0 writes
    if (l == 0) {
        const float* ac = cur ? al1 : al0;
        float a[K];
#pragma unroll
        for (int c = 0; c < 6; ++c) {
            float4 v = *(const float4*)(ac + 4*c);
            a[4*c] = v.x; a[4*c+1] = v.y; a[4*c+2] = v.z; a[4*c+3] = v.w;
        }
        float m; int p;
        argmax24(a, m, p);
        if (WS) tag_ws[(size_t)b * T + (T - 1)] = (uint8_t)p;
        else    obw[18] = (uint32_t)p;
    }
}

// ---------------------------------------------------------------------------
// Chase: follow backpointers, 1 thread/batch (unchanged from round 2).
// ---------------------------------------------------------------------------
template<bool WS>
__global__ __launch_bounds__(64) void crf_chase(
    float* __restrict__ out,
    const uint8_t* __restrict__ bp_ws,
    uint8_t* __restrict__ tag_ws)
{
    const int b = blockIdx.x * 64 + threadIdx.x;
    uint32_t*       obw = (uint32_t*)out + (size_t)b * T * K;
    const uint8_t*  bpb = WS ? (bp_ws + (size_t)b * T * K) : nullptr;
    uint8_t*        tgb = WS ? (tag_ws + (size_t)b * T) : nullptr;

    uint32_t w[4][8][6];

#define LOADG(GG, SLOT) do {                                                  \
    int gg_ = (GG);                                                           \
    if (gg_ < 64) {                                                           \
      _Pragma("unroll")                                                       \
      for (int q_ = 0; q_ < 8; ++q_) {                                        \
        int u_ = 511 - 8 * gg_ - q_;                                          \
        const uint32_t* r_;                                                   \
        if (WS) r_ = (const uint32_t*)(bpb + (size_t)u_ * K);                 \
        else    r_ = obw + (size_t)u_ * K + 18;                               \
        *(uint2*)&w[SLOT][q_][0] = *(const uint2*)(r_);                       \
        *(uint2*)&w[SLOT][q_][2] = *(const uint2*)(r_ + 2);                   \
        *(uint2*)&w[SLOT][q_][4] = *(const uint2*)(r_ + 4);                   \
      }                                                                       \
    }                                                                         \
  } while (0)

#define PROCG(GG, SLOT) do {                                                  \
    int gg_ = (GG);                                                           \
    _Pragma("unroll")                                                         \
    for (int q_ = 0; q_ < 8; ++q_) {                                          \
      int u_ = 511 - 8 * gg_ - q_;                                            \
      if (u_ > 0) {                                                           \
        int idx_ = cur >> 2;                                                  \
        uint32_t wA_ = (idx_ & 1) ? w[SLOT][q_][1] : w[SLOT][q_][0];          \
        uint32_t wB_ = (idx_ & 1) ? w[SLOT][q_][3] : w[SLOT][q_][2];          \
        uint32_t wC_ = (idx_ & 1) ? w[SLOT][q_][5] : w[SLOT][q_][4];          \
        uint32_t wAB_ = (idx_ & 2) ? wB_ : wA_;                               \
        uint32_t wd_  = (idx_ & 4) ? wC_ : wAB_;                              \
        int nxt_ = (int)((wd_ >> ((cur & 3) * 8)) & 0xFF);                    \
        if (WS) tgb[u_] = (uint8_t)cur;                                       \
        else    obw[(size_t)u_ * K + 18] = (uint32_t)cur;                     \
        cur = nxt_;                                                           \
      } else {                                                                \
        if (WS) tgb[0] = (uint8_t)cur;                                        \
        else    obw[18] = (uint32_t)cur;                                      \
      }                                                                       \
    }                                                                         \
  } while (0)

    int cur;
    if (WS) cur = (int)tgb[T - 1];
    else    cur = (int)obw[18];

    LOADG(0, 0); LOADG(1, 1); LOADG(2, 2); LOADG(3, 3);

#pragma unroll 1
    for (int base = 0; base < 60; base += 4) {
        PROCG(base + 0, 0); LOADG(base + 4, 0);
        PROCG(base + 1, 1); LOADG(base + 5, 1);
        PROCG(base + 2, 2); LOADG(base + 6, 2);
        PROCG(base + 3, 3); LOADG(base + 7, 3);
    }
    PROCG(60, 0); PROCG(61, 1); PROCG(62, 2); PROCG(63, 3);
#undef LOADG
#undef PROCG
}

// ---------------------------------------------------------------------------
// One-hot scatter: one thread per (b,t) (unchanged from round 2).
// ---------------------------------------------------------------------------
template<bool WS>
__global__ __launch_bounds__(256) void crf_onehot(
    float* __restrict__ out, const uint8_t* __restrict__ tag_ws)
{
    const size_t idx = (size_t)blockIdx.x * 256 + threadIdx.x;  // < B*T
    uint32_t* rec = (uint32_t*)out + idx * K;
    int tag;
    if (WS) tag = (int)tag_ws[idx];
    else    tag = (int)rec[18];
#pragma unroll
    for (int c = 0; c < 6; ++c) {
        uint4 v;
        v.x = (tag == 4*c+0) ? 0x3F800000u : 0u;
        v.y = (tag == 4*c+1) ? 0x3F800000u : 0u;
        v.z = (tag == 4*c+2) ? 0x3F800000u : 0u;
        v.w = (tag == 4*c+3) ? 0x3F800000u : 0u;
        *(uint4*)(rec + 4*c) = v;
    }
}

extern "C" void kernel_launch(void* const* d_in, const int* in_sizes, int n_in,
                              void* d_out, int out_size, void* d_ws, size_t ws_size,
                              hipStream_t stream) {
    const float* inp   = (const float*)d_in[0];   // [8192, 512, 24]
    const float* trans = (const float*)d_in[1];   // [24, 24]
    float*       out   = (float*)d_out;           // [8192, 512, 24]

    const size_t need = (size_t)B * T * K + (size_t)B * T;  // bp + tags
    if (ws_size >= need) {
        uint8_t* bp = (uint8_t*)d_ws;
        uint8_t* tg = (uint8_t*)d_ws + (size_t)B * T * K;
        crf_forward<true><<<B / 32, 256, 0, stream>>>(inp, trans, out, bp, tg);
        crf_chase<true><<<B / 64, 64, 0, stream>>>(out, bp, tg);
        crf_onehot<true><<<(B * T) / 256, 256, 0, stream>>>(out, tg);
    } else {
        crf_forward<false><<<B / 32, 256, 0, stream>>>(inp, trans, out, nullptr, nullptr);
        crf_chase<false><<<B / 64, 64, 0, stream>>>(out, nullptr, nullptr);
        crf_onehot<false><<<(B * T) / 256, 256, 0, stream>>>(out, nullptr);
    }
}